// Round 1
// baseline (184.795 us; speedup 1.0000x reference)
//
#include <hip/hip_runtime.h>
#include <hip/hip_bf16.h>

// Problem constants
#define Bk 8
#define Nk 10000
#define Ek 160000
#define Hk 128
#define Zk 64
#define NPk 10112   // 79*128, per-batch padded row count

typedef float f32x4 __attribute__((ext_vector_type(4)));
typedef short s16x8 __attribute__((ext_vector_type(8)));

__global__ void k0_zero(int* deg, int* cur, float* pooled){
  int t = blockIdx.x*blockDim.x + threadIdx.x;
  if (t < Nk){ deg[t]=0; cur[t]=0; }
  if (t < Bk*Hk) pooled[t]=0.f;
}

__global__ void k1_deg(const int* ei, int* deg){
  int e = blockIdx.x*blockDim.x + threadIdx.x;
  if (e < Ek) atomicAdd(&deg[ei[Ek+e]], 1);
}

// single-block exclusive scan over deg[0..N) -> rowofs[0..N]
__global__ void k2_scan(const int* deg, int* rowofs){
  __shared__ int s[1024];
  const int CH = 10; // 1024*10 >= Nk
  int t = threadIdx.x;
  int base = t*CH;
  int loc = 0;
  for (int k=0;k<CH;k++){ int idx=base+k; if(idx<Nk) loc += deg[idx]; }
  s[t]=loc; __syncthreads();
  for (int off=1; off<1024; off<<=1){
    int v = (t>=off) ? s[t-off] : 0;
    __syncthreads();
    s[t] += v;
    __syncthreads();
  }
  int run = (t>0) ? s[t-1] : 0;
  for (int k=0;k<CH;k++){
    int idx=base+k;
    if (idx<Nk){ rowofs[idx]=run; run+=deg[idx]; }
  }
  if (t==1023) rowofs[Nk]=s[1023];
}

__global__ void k3_fill(const int* ei, const int* rowofs, int* cur, int* csrsrc){
  int e = blockIdx.x*blockDim.x + threadIdx.x;
  if (e < Ek){
    int srcv = ei[e], d = ei[Ek+e];
    int p = atomicAdd(&cur[d], 1);
    csrsrc[rowofs[d]+p] = srcv;
  }
}

// agg1[b,i] = mean over incoming edges of x[b,src]
__global__ void k4_agg1(const float* x, const int* rowofs, const int* csrsrc, float* agg1){
  int i = blockIdx.x*blockDim.x + threadIdx.x;
  int b = blockIdx.y;
  if (i >= Nk) return;
  int r0=rowofs[i], r1=rowofs[i+1];
  const float* xb = x + b*Nk;
  float sum=0.f;
  for (int k=r0;k<r1;k++) sum += xb[csrsrc[k]];
  agg1[b*Nk+i] = sum / fmaxf((float)(r1-r0), 1.f);
}

// WBT[o][k] (128x256 bf16): k<128 -> W2l[o][k], else W2r[o][k-128]
__global__ void k5b_wbt(const float* W2l, const float* W2r, __hip_bfloat16* wbt){
  int t = blockIdx.x*blockDim.x + threadIdx.x;
  if (t >= 128*256) return;
  int o = t >> 8, k = t & 255;
  float v = (k < 128) ? W2l[o*128+k] : W2r[o*128+(k-128)];
  wbt[t] = __float2bfloat16(v);
}

// XMAT[b*NP+i][0:128]=AGG2, [128:256]=H1  (bf16). h1 recomputed per edge from 2 scalars.
__global__ void k5_xmat(const float* x, const float* agg1, const int* rowofs, const int* csrsrc,
                        const float* W1l, const float* b1, const float* W1r,
                        __hip_bfloat16* xmat){
  int i = blockIdx.x, b = blockIdx.y, h = threadIdx.x;
  __hip_bfloat16* out = xmat + ((size_t)b*NPk + i)*256;
  if (i >= Nk){ out[h]=__float2bfloat16(0.f); out[128+h]=__float2bfloat16(0.f); return; }
  float w1l=W1l[h], w1r=W1r[h], bb=b1[h];
  int r0=rowofs[i], r1=rowofs[i+1];
  const float* xb = x + b*Nk;
  const float* ab = agg1 + b*Nk;
  float acc=0.f;
  for (int k=r0;k<r1;k++){
    int j = csrsrc[k];
    acc += fmaxf(ab[j]*w1l + xb[j]*w1r + bb, 0.f);
  }
  float agg2 = acc / fmaxf((float)(r1-r0), 1.f);
  float h1 = fmaxf(ab[i]*w1l + xb[i]*w1r + bb, 0.f);
  out[h]     = __float2bfloat16(agg2);
  out[128+h] = __float2bfloat16(h1);
}

__device__ inline void mfma_bf16(f32x4& d, s16x8 a, s16x8 b){
  asm("v_mfma_f32_16x16x32_bf16 %0, %1, %2, %0" : "+v"(d) : "v"(a), "v"(b));
}

// GEMM (NPk rows x 256) @ WBT^T (256 x 128), relu+bias, column-sum into pooled (atomic).
// block=256 (4 waves), each wave: 32 rows x 128 cols. A streamed from global,
// B (64KB) L2-resident, no LDS (A has zero reuse, B is cache-hot).
__global__ __launch_bounds__(256) void k6_gemm(const __hip_bfloat16* xmat, const __hip_bfloat16* wbt,
                                               const float* b2, float* pooled){
  int wid = threadIdx.x >> 6, lane = threadIdx.x & 63;
  int b = blockIdx.y;
  int row0 = blockIdx.x*128 + wid*32;       // within NPk
  int lr = lane & 15, lk = lane >> 4;
  const __hip_bfloat16* xbase = xmat + ((size_t)b*NPk + row0)*256;

  f32x4 acc[2][8];
  #pragma unroll
  for (int mf=0; mf<2; ++mf)
    #pragma unroll
    for (int nf=0; nf<8; ++nf) acc[mf][nf] = (f32x4){0.f,0.f,0.f,0.f};

  for (int kk=0; kk<8; ++kk){
    int ko = kk*32 + lk*8;
    s16x8 a0 = *(const s16x8*)(const void*)(xbase + lr*256 + ko);
    s16x8 a1 = *(const s16x8*)(const void*)(xbase + (16+lr)*256 + ko);
    #pragma unroll
    for (int nf=0; nf<8; ++nf){
      s16x8 bfr = *(const s16x8*)(const void*)(wbt + (nf*16+lr)*256 + ko);
      mfma_bf16(acc[0][nf], a0, bfr);
      mfma_bf16(acc[1][nf], a1, bfr);
    }
  }

  // epilogue: relu(acc + b2), mask pad rows, column-reduce, atomic into pooled
  #pragma unroll
  for (int nf=0; nf<8; ++nf){
    int col = nf*16 + lr;
    float bias = b2[col];
    float v = 0.f;
    #pragma unroll
    for (int mf=0; mf<2; ++mf){
      int rbase = row0 + mf*16 + lk*4;
      #pragma unroll
      for (int r=0;r<4;++r){
        float val = fmaxf(acc[mf][nf][r] + bias, 0.f);
        if (rbase + r < Nk) v += val;
      }
    }
    v += __shfl_xor(v, 16);
    v += __shfl_xor(v, 32);
    if (lane < 16) atomicAdd(&pooled[b*Hk + col], v);
  }
}

__global__ void k7_final(const float* pooled, const float* Wro1, const float* bro1,
                         const float* Wro2, const float* bro2, float* out){
  int b = blockIdx.x, t = threadIdx.x;
  __shared__ float pool[128];
  __shared__ float hid[128];
  pool[t] = pooled[b*Hk + t] * (1.0f/(float)Nk);
  __syncthreads();
  float s = bro1[t];
  for (int d=0; d<128; ++d) s += Wro1[t*128+d]*pool[d];
  hid[t] = fmaxf(s, 0.f);
  __syncthreads();
  if (t < Zk){
    float s2 = bro2[t];
    for (int d=0; d<128; ++d) s2 += Wro2[t*128+d]*hid[d];
    out[b*Zk + t] = s2;
  }
}

extern "C" void kernel_launch(void* const* d_in, const int* in_sizes, int n_in,
                              void* d_out, int out_size, void* d_ws, size_t ws_size,
                              hipStream_t stream) {
  const float* x    = (const float*)d_in[0];
  const int*   ei   = (const int*)d_in[1];
  const float* W1l  = (const float*)d_in[2];
  const float* b1   = (const float*)d_in[3];
  const float* W1r  = (const float*)d_in[4];
  const float* W2l  = (const float*)d_in[5];
  const float* b2   = (const float*)d_in[6];
  const float* W2r  = (const float*)d_in[7];
  const float* Wro1 = (const float*)d_in[8];
  const float* bro1 = (const float*)d_in[9];
  const float* Wro2 = (const float*)d_in[10];
  const float* bro2 = (const float*)d_in[11];
  float* out = (float*)d_out;

  // workspace layout (bytes, 256-aligned); total ~42.6 MB
  char* ws = (char*)d_ws;
  int*   deg    = (int*)(ws + 0);            // 40000
  int*   cur    = (int*)(ws + 40448);        // 40000
  int*   rowofs = (int*)(ws + 80896);        // 40004
  int*   csrsrc = (int*)(ws + 121344);       // 640000
  float* agg1   = (float*)(ws + 761856);     // 320000
  float* pooled = (float*)(ws + 1082368);    // 4096
  __hip_bfloat16* wbt  = (__hip_bfloat16*)(ws + 1086464);  // 65536
  __hip_bfloat16* xmat = (__hip_bfloat16*)(ws + 1152000);  // 8*10112*256*2 = 41418752

  k0_zero<<<dim3((Nk+255)/256), 256, 0, stream>>>(deg, cur, pooled);
  k1_deg <<<dim3((Ek+255)/256), 256, 0, stream>>>(ei, deg);
  k2_scan<<<dim3(1), 1024, 0, stream>>>(deg, rowofs);
  k3_fill<<<dim3((Ek+255)/256), 256, 0, stream>>>(ei, rowofs, cur, csrsrc);
  k5b_wbt<<<dim3(128), 256, 0, stream>>>(W2l, W2r, wbt);
  k4_agg1<<<dim3((Nk+255)/256, Bk), 256, 0, stream>>>(x, rowofs, csrsrc, agg1);
  k5_xmat<<<dim3(NPk, Bk), 128, 0, stream>>>(x, agg1, rowofs, csrsrc, W1l, b1, W1r, xmat);
  k6_gemm<<<dim3(NPk/128, Bk), 256, 0, stream>>>(xmat, wbt, b2, pooled);
  k7_final<<<dim3(Bk), 128, 0, stream>>>(pooled, Wro1, bro1, Wro2, bro2, out);
}

// Round 2
// 133.863 us; speedup vs baseline: 1.3805x; 1.3805x over previous
//
#include <hip/hip_runtime.h>
#include <hip/hip_bf16.h>

// Problem constants
#define Bk 8
#define Nk 10000
#define Ek 160000
#define Hk 128
#define Zk 64
#define NPk 10112   // 79*128, per-batch padded row count

typedef float f32x4 __attribute__((ext_vector_type(4)));
typedef short s16x8 __attribute__((ext_vector_type(8)));

__global__ void k0_zero(int* deg, int* cur, float* pooled){
  int t = blockIdx.x*blockDim.x + threadIdx.x;
  if (t < Nk){ deg[t]=0; cur[t]=0; }
  if (t < Bk*Hk) pooled[t]=0.f;
}

__global__ void k1_deg(const int* ei, int* deg){
  int e = blockIdx.x*blockDim.x + threadIdx.x;
  if (e < Ek) atomicAdd(&deg[ei[Ek+e]], 1);
}

// single-block exclusive scan over deg[0..N) -> rowofs[0..N]
__global__ void k2_scan(const int* deg, int* rowofs){
  __shared__ int s[1024];
  const int CH = 10; // 1024*10 >= Nk
  int t = threadIdx.x;
  int base = t*CH;
  int loc = 0;
  for (int k=0;k<CH;k++){ int idx=base+k; if(idx<Nk) loc += deg[idx]; }
  s[t]=loc; __syncthreads();
  for (int off=1; off<1024; off<<=1){
    int v = (t>=off) ? s[t-off] : 0;
    __syncthreads();
    s[t] += v;
    __syncthreads();
  }
  int run = (t>0) ? s[t-1] : 0;
  for (int k=0;k<CH;k++){
    int idx=base+k;
    if (idx<Nk){ rowofs[idx]=run; run+=deg[idx]; }
  }
  if (t==1023) rowofs[Nk]=s[1023];
}

__global__ void k3_fill(const int* ei, const int* rowofs, int* cur, int* csrsrc){
  int e = blockIdx.x*blockDim.x + threadIdx.x;
  if (e < Ek){
    int srcv = ei[e], d = ei[Ek+e];
    int p = atomicAdd(&cur[d], 1);
    csrsrc[rowofs[d]+p] = srcv;
  }
}

// agg1[b,i] = mean over incoming edges of x[b,src]
__global__ void k4_agg1(const float* x, const int* rowofs, const int* csrsrc, float* agg1){
  int i = blockIdx.x*blockDim.x + threadIdx.x;
  int b = blockIdx.y;
  if (i >= Nk) return;
  int r0=rowofs[i], r1=rowofs[i+1];
  const float* xb = x + b*Nk;
  float sum=0.f;
  for (int k=r0;k<r1;k++) sum += xb[csrsrc[k]];
  agg1[b*Nk+i] = sum / fmaxf((float)(r1-r0), 1.f);
}

// WBT[o][k] (128x256 bf16): k<128 -> W2l[o][k], else W2r[o][k-128]
__global__ void k5b_wbt(const float* W2l, const float* W2r, __hip_bfloat16* wbt){
  int t = blockIdx.x*blockDim.x + threadIdx.x;
  if (t >= 128*256) return;
  int o = t >> 8, k = t & 255;
  float v = (k < 128) ? W2l[o*128+k] : W2r[o*128+(k-128)];
  wbt[t] = __float2bfloat16(v);
}

// XMAT[b*NP+i][0:128]=AGG2, [128:256]=H1  (bf16).
// Block per node (all 8 batches). Phase 1: 128 threads = 16 edge-slots x 8
// batches cooperatively gather (agg1, x) pairs into LDS. Phase 2: thread = h,
// LDS-broadcast loop computes acc[b] += relu(a*w1l + x*w1r + b1).
__global__ __launch_bounds__(128) void k5_xmat(const float* x, const float* agg1,
                        const int* rowofs, const int* csrsrc,
                        const float* W1l, const float* b1, const float* W1r,
                        __hip_bfloat16* xmat){
  int i = blockIdx.x, t = threadIdx.x;
  if (i >= Nk){
    #pragma unroll
    for (int b=0;b<Bk;b++){
      __hip_bfloat16* o = xmat + ((size_t)b*NPk + i)*256;
      o[t]     = __float2bfloat16(0.f);
      o[128+t] = __float2bfloat16(0.f);
    }
    return;
  }
  __shared__ float2 sax[Bk][16];   // [batch][edge-slot] = (agg1_j, x_j)
  int r0 = rowofs[i], deg = rowofs[i+1]-r0;
  float w1l=W1l[t], w1r=W1r[t], bb=b1[t];
  float acc[Bk];
  #pragma unroll
  for (int b=0;b<Bk;b++) acc[b]=0.f;

  int kslot = t>>3, bslot = t&7;
  for (int base=0; base<deg; base+=16){
    int cnt = min(16, deg-base);
    if (kslot < cnt){
      int j = csrsrc[r0+base+kslot];
      sax[bslot][kslot] = make_float2(agg1[bslot*Nk+j], x[bslot*Nk+j]);
    }
    __syncthreads();
    #pragma unroll
    for (int b2=0;b2<Bk;b2++){
      #pragma unroll 4
      for (int k2=0;k2<cnt;k2++){
        float2 v = sax[b2][k2];
        acc[b2] += fmaxf(v.x*w1l + v.y*w1r + bb, 0.f);
      }
    }
    __syncthreads();
  }

  float inv = 1.f/fmaxf((float)deg,1.f);
  #pragma unroll
  for (int b=0;b<Bk;b++){
    float a_i = agg1[b*Nk+i], x_i = x[b*Nk+i];
    float h1 = fmaxf(a_i*w1l + x_i*w1r + bb, 0.f);
    __hip_bfloat16* o = xmat + ((size_t)b*NPk + i)*256;
    o[t]     = __float2bfloat16(acc[b]*inv);
    o[128+t] = __float2bfloat16(h1);
  }
}

__device__ inline void mfma_bf16(f32x4& d, s16x8 a, s16x8 b){
  asm("v_mfma_f32_16x16x32_bf16 %0, %1, %2, %0" : "+v"(d) : "v"(a), "v"(b));
}

// GEMM (NPk rows x 256) @ WBT^T (256 x 128), relu+bias, column-sum into pooled (atomic).
__global__ __launch_bounds__(256) void k6_gemm(const __hip_bfloat16* xmat, const __hip_bfloat16* wbt,
                                               const float* b2, float* pooled){
  int wid = threadIdx.x >> 6, lane = threadIdx.x & 63;
  int b = blockIdx.y;
  int row0 = blockIdx.x*128 + wid*32;       // within NPk
  int lr = lane & 15, lk = lane >> 4;
  const __hip_bfloat16* xbase = xmat + ((size_t)b*NPk + row0)*256;

  f32x4 acc[2][8];
  #pragma unroll
  for (int mf=0; mf<2; ++mf)
    #pragma unroll
    for (int nf=0; nf<8; ++nf) acc[mf][nf] = (f32x4){0.f,0.f,0.f,0.f};

  for (int kk=0; kk<8; ++kk){
    int ko = kk*32 + lk*8;
    s16x8 a0 = *(const s16x8*)(const void*)(xbase + lr*256 + ko);
    s16x8 a1 = *(const s16x8*)(const void*)(xbase + (16+lr)*256 + ko);
    #pragma unroll
    for (int nf=0; nf<8; ++nf){
      s16x8 bfr = *(const s16x8*)(const void*)(wbt + (nf*16+lr)*256 + ko);
      mfma_bf16(acc[0][nf], a0, bfr);
      mfma_bf16(acc[1][nf], a1, bfr);
    }
  }

  // epilogue: relu(acc + b2), mask pad rows, column-reduce, atomic into pooled
  #pragma unroll
  for (int nf=0; nf<8; ++nf){
    int col = nf*16 + lr;
    float bias = b2[col];
    float v = 0.f;
    #pragma unroll
    for (int mf=0; mf<2; ++mf){
      int rbase = row0 + mf*16 + lk*4;
      #pragma unroll
      for (int r=0;r<4;++r){
        float val = fmaxf(acc[mf][nf][r] + bias, 0.f);
        if (rbase + r < Nk) v += val;
      }
    }
    v += __shfl_xor(v, 16);
    v += __shfl_xor(v, 32);
    if (lane < 16) atomicAdd(&pooled[b*Hk + col], v);
  }
}

__global__ void k7_final(const float* pooled, const float* Wro1, const float* bro1,
                         const float* Wro2, const float* bro2, float* out){
  int b = blockIdx.x, t = threadIdx.x;
  __shared__ float pool[128];
  __shared__ float hid[128];
  pool[t] = pooled[b*Hk + t] * (1.0f/(float)Nk);
  __syncthreads();
  float s = bro1[t];
  for (int d=0; d<128; ++d) s += Wro1[t*128+d]*pool[d];
  hid[t] = fmaxf(s, 0.f);
  __syncthreads();
  if (t < Zk){
    float s2 = bro2[t];
    for (int d=0; d<128; ++d) s2 += Wro2[t*128+d]*hid[d];
    out[b*Zk + t] = s2;
  }
}

extern "C" void kernel_launch(void* const* d_in, const int* in_sizes, int n_in,
                              void* d_out, int out_size, void* d_ws, size_t ws_size,
                              hipStream_t stream) {
  const float* x    = (const float*)d_in[0];
  const int*   ei   = (const int*)d_in[1];
  const float* W1l  = (const float*)d_in[2];
  const float* b1   = (const float*)d_in[3];
  const float* W1r  = (const float*)d_in[4];
  const float* W2l  = (const float*)d_in[5];
  const float* b2   = (const float*)d_in[6];
  const float* W2r  = (const float*)d_in[7];
  const float* Wro1 = (const float*)d_in[8];
  const float* bro1 = (const float*)d_in[9];
  const float* Wro2 = (const float*)d_in[10];
  const float* bro2 = (const float*)d_in[11];
  float* out = (float*)d_out;

  // workspace layout (bytes, 256-aligned); total ~42.6 MB
  char* ws = (char*)d_ws;
  int*   deg    = (int*)(ws + 0);            // 40000
  int*   cur    = (int*)(ws + 40448);        // 40000
  int*   rowofs = (int*)(ws + 80896);        // 40004
  int*   csrsrc = (int*)(ws + 121344);       // 640000
  float* agg1   = (float*)(ws + 761856);     // 320000
  float* pooled = (float*)(ws + 1082368);    // 4096
  __hip_bfloat16* wbt  = (__hip_bfloat16*)(ws + 1086464);  // 65536
  __hip_bfloat16* xmat = (__hip_bfloat16*)(ws + 1152000);  // 8*10112*256*2 = 41418752

  k0_zero<<<dim3((Nk+255)/256), 256, 0, stream>>>(deg, cur, pooled);
  k1_deg <<<dim3((Ek+255)/256), 256, 0, stream>>>(ei, deg);
  k2_scan<<<dim3(1), 1024, 0, stream>>>(deg, rowofs);
  k3_fill<<<dim3((Ek+255)/256), 256, 0, stream>>>(ei, rowofs, cur, csrsrc);
  k5b_wbt<<<dim3(128), 256, 0, stream>>>(W2l, W2r, wbt);
  k4_agg1<<<dim3((Nk+255)/256, Bk), 256, 0, stream>>>(x, rowofs, csrsrc, agg1);
  k5_xmat<<<dim3(NPk), 128, 0, stream>>>(x, agg1, rowofs, csrsrc, W1l, b1, W1r, xmat);
  k6_gemm<<<dim3(NPk/128, Bk), 256, 0, stream>>>(xmat, wbt, b2, pooled);
  k7_final<<<dim3(Bk), 128, 0, stream>>>(pooled, Wro1, bro1, Wro2, bro2, out);
}